// Round 7
// baseline (357.595 us; speedup 1.0000x reference)
//
#include <hip/hip_runtime.h>
#include <math.h>

#define N_ROWS 32768
#define DIM 256
#define K_CODES 1024
#define MARGIN 2e-3f

typedef float f32x4v __attribute__((ext_vector_type(4)));
typedef short s16x8 __attribute__((ext_vector_type(8)));

// ---- ws layout ----
// x2   : float[32768]                     @ 0
// w2   : float[1024]                      @ 32768*4
// whi  : ushort[1024*256]                 @ 33792*4
// wlo  : ushort[1024*256]                 @ 33792*4 + 524288
// total = 1,183,744 B  (== proven available in rounds 5/6)
#define WS_NEEDED ((size_t)33792 * 4 + 2 * (size_t)K_CODES * DIM * 2)

__device__ __forceinline__ unsigned short bf16_rne(float f) {
    unsigned int u = __float_as_uint(f);
    unsigned int r = (u + 0x7FFFu + ((u >> 16) & 1u)) >> 16;
    return (unsigned short)r;
}
__device__ __forceinline__ float bf16_f32(unsigned short h) {
    return __uint_as_float(((unsigned int)h) << 16);
}

// ---------------------------------------------------------------------------
// numpy-replica pairwise sum of squares (AVX512 path) — bitwise == np.sum(x*x)
// ---------------------------------------------------------------------------
__device__ __forceinline__ float np_block128_sumsq(const float* e) {
#pragma clang fp contract(off)
    float s[16];
#pragma unroll
    for (int l = 0; l < 16; ++l) {
        float a0 = e[l]       * e[l];
        float a1 = e[16 + l]  * e[16 + l];
        float a2 = e[32 + l]  * e[32 + l];
        float a3 = e[48 + l]  * e[48 + l];
        float a4 = e[64 + l]  * e[64 + l];
        float a5 = e[80 + l]  * e[80 + l];
        float a6 = e[96 + l]  * e[96 + l];
        float a7 = e[112 + l] * e[112 + l];
        s[l] = ((a0 + a1) + (a2 + a3)) + ((a4 + a5) + (a6 + a7));
    }
    float t1[8];
#pragma unroll
    for (int i = 0; i < 8; ++i) t1[i] = s[i] + s[i + 8];
    float t2[4];
#pragma unroll
    for (int i = 0; i < 4; ++i) t2[i] = t1[i] + t1[i + 4];
    return (t2[0] + t2[2]) + (t2[1] + t2[3]);
}

__global__ __launch_bounds__(64) void npsumsq_kernel(const float* __restrict__ src,
                                                     float* __restrict__ dst) {
    __shared__ float buf[16][257];
    const int tid = threadIdx.x;
    const int r0 = blockIdx.x * 16;
#pragma unroll
    for (int it = 0; it < 16; ++it) {
        int idx = it * 64 + tid;
        int r = idx >> 6, c4 = idx & 63;
        float4 v = ((const float4*)(src + (size_t)(r0 + r) * DIM))[c4];
        buf[r][c4 * 4 + 0] = v.x;
        buf[r][c4 * 4 + 1] = v.y;
        buf[r][c4 * 4 + 2] = v.z;
        buf[r][c4 * 4 + 3] = v.w;
    }
    __syncthreads();
    if (tid < 16) {
        const float* e = buf[tid];
        dst[r0 + tid] = np_block128_sumsq(e) + np_block128_sumsq(e + 128);
    }
}

// ---------------------------------------------------------------------------
// W -> bf16 hi/lo split
// ---------------------------------------------------------------------------
__global__ __launch_bounds__(256) void wsplit_kernel(const float* __restrict__ w,
                                                     unsigned short* __restrict__ whi,
                                                     unsigned short* __restrict__ wlo) {
    int i = blockIdx.x * 256 + threadIdx.x;   // grid 1024 -> covers 262144
    float v = w[i];
    unsigned short h = bf16_rne(v);
    whi[i] = h;
    wlo[i] = bf16_rne(v - bf16_f32(h));
}

__global__ void zero_kernel(int* p) { if (threadIdx.x == 0) p[0] = 0; }

// ---------------------------------------------------------------------------
// Main: split-bf16 MFMA scoring + per-row top-2 + margin flagging.
// Block = 4 waves x 16 rows = 64 rows, all 1024 codes. Grid 512.
// A-frag: row = lane&15, k = (lane>>4)*8 + i  (built from f32 X, split inline)
// B-frag: col = lane&15 (code), same k mapping (from whi/wlo)
// D     : col = lane&15, row = (lane>>4)*4 + j   [m89-verified]
// ---------------------------------------------------------------------------
__global__ __launch_bounds__(256) void vq_mfma(
    const float* __restrict__ x, const unsigned short* __restrict__ whi,
    const unsigned short* __restrict__ wlo, const float* __restrict__ x2g,
    const float* __restrict__ w2g, float* __restrict__ zout,
    int* __restrict__ flagcnt, int* __restrict__ flaglist) {
    const int tid = threadIdx.x;
    const int wave = tid >> 6;
    const int lane = tid & 63;
    const int rowbase = blockIdx.x * 64 + wave * 16;
    const int kgrp = (lane >> 4) * 8;

    // ---- build A fragments (held in regs for the whole kernel) ----
    s16x8 ahi[8], alo[8];
    {
        const float* xr = x + (size_t)(rowbase + (lane & 15)) * DIM + kgrp;
#pragma unroll
        for (int q = 0; q < 8; ++q) {
            float4 v0 = *(const float4*)(xr + q * 32);
            float4 v1 = *(const float4*)(xr + q * 32 + 4);
            float e[8] = {v0.x, v0.y, v0.z, v0.w, v1.x, v1.y, v1.z, v1.w};
#pragma unroll
            for (int i = 0; i < 8; ++i) {
                unsigned short h = bf16_rne(e[i]);
                ahi[q][i] = (short)h;
                alo[q][i] = (short)bf16_rne(e[i] - bf16_f32(h));
            }
        }
    }

    float x2v[4];
#pragma unroll
    for (int j = 0; j < 4; ++j) x2v[j] = x2g[rowbase + (lane >> 4) * 4 + j];

    float b1[4], b2[4];
    int i1[4];
#pragma unroll
    for (int j = 0; j < 4; ++j) { b1[j] = INFINITY; b2[j] = INFINITY; i1[j] = 0; }

    for (int ct = 0; ct < 64; ++ct) {
        const int code = ct * 16 + (lane & 15);
        const unsigned short* bh = whi + (size_t)code * DIM + kgrp;
        const unsigned short* bl = wlo + (size_t)code * DIM + kgrp;
        f32x4v acc = {0.f, 0.f, 0.f, 0.f};
#pragma unroll
        for (int q = 0; q < 8; ++q) {
            s16x8 Bh = *(const s16x8*)(bh + q * 32);
            s16x8 Bl = *(const s16x8*)(bl + q * 32);
            acc = __builtin_amdgcn_mfma_f32_16x16x32_bf16(ahi[q], Bh, acc, 0, 0, 0);
            acc = __builtin_amdgcn_mfma_f32_16x16x32_bf16(ahi[q], Bl, acc, 0, 0, 0);
            acc = __builtin_amdgcn_mfma_f32_16x16x32_bf16(alo[q], Bh, acc, 0, 0, 0);
        }
        float w2v = w2g[code];
#pragma unroll
        for (int j = 0; j < 4; ++j) {
            float s = (x2v[j] - 2.0f * acc[j]) + w2v;
            if (s < b2[j]) {
                if (s < b1[j]) { b2[j] = b1[j]; b1[j] = s; i1[j] = code; }
                else b2[j] = s;
            }
        }
    }

    // butterfly top-2 reduce across the 16-lane col group (masks 1,2,4,8)
#pragma unroll
    for (int m = 1; m < 16; m <<= 1) {
#pragma unroll
        for (int j = 0; j < 4; ++j) {
            float ov1 = __shfl_xor(b1[j], m);
            int oi = __shfl_xor(i1[j], m);
            float ov2 = __shfl_xor(b2[j], m);
            float nb2 = fminf(fmaxf(b1[j], ov1), fminf(b2[j], ov2));
            if (ov1 < b1[j] || (ov1 == b1[j] && oi < i1[j])) { b1[j] = ov1; i1[j] = oi; }
            b2[j] = nb2;
        }
    }

    if ((lane & 15) == 0) {
#pragma unroll
        for (int j = 0; j < 4; ++j) {
            int r = rowbase + (lane >> 4) * 4 + j;
            zout[r] = (float)i1[j];
            if (b2[j] - b1[j] < MARGIN) {
                int slot = atomicAdd(flagcnt, 1);
                flaglist[slot] = r;
            }
        }
    }
}

// ---------------------------------------------------------------------------
// Exact np-f32 rescore of flagged rows (round-5-verified semantics).
// ---------------------------------------------------------------------------
__global__ __launch_bounds__(256) void rescue_kernel(
    const float* __restrict__ x, const float* __restrict__ w,
    const float* __restrict__ x2g, const float* __restrict__ w2g,
    const int* __restrict__ flagcnt, const int* __restrict__ flaglist,
    float* __restrict__ zout) {
    __shared__ float xs[DIM];
    __shared__ float dv[256];
    __shared__ int di[256];
    const int tid = threadIdx.x;
    const int cnt = flagcnt[0];
    for (int f = blockIdx.x; f < cnt; f += gridDim.x) {
        const int r = flaglist[f];
        __syncthreads();
        for (int i = tid; i < DIM; i += 256) xs[i] = x[(size_t)r * DIM + i];
        __syncthreads();
        const float x2vv = x2g[r];
        float bv = INFINITY;
        int bi = 0;
#pragma unroll
        for (int cc = 0; cc < 4; ++cc) {
            int c = tid + cc * 256;
            const float* wr = w + (size_t)c * DIM;
            float dot = 0.f;
            for (int k = 0; k < DIM; ++k) dot = __builtin_fmaf(xs[k], wr[k], dot);
            float s = (x2vv - 2.0f * dot) + w2g[c];
            if (s < bv || (s == bv && c < bi)) { bv = s; bi = c; }
        }
        dv[tid] = bv;
        di[tid] = bi;
        __syncthreads();
        if (tid == 0) {
            float mv = dv[0];
            int mi = di[0];
            for (int t = 1; t < 256; ++t)
                if (dv[t] < mv || (dv[t] == mv && di[t] < mi)) { mv = dv[t]; mi = di[t]; }
            zout[r] = (float)mi;
        }
    }
}

// ---------------------------------------------------------------------------
// Gather z_q from final indices.
// ---------------------------------------------------------------------------
__global__ __launch_bounds__(256) void gather_kernel(const float* __restrict__ zout,
                                                     const float* __restrict__ w,
                                                     float* __restrict__ zq) {
    const int tid = threadIdx.x;
    const int bm0 = blockIdx.x * 16;
    __shared__ int widx[16];
    if (tid < 16) widx[tid] = (int)zout[bm0 + tid];
    __syncthreads();
    const float4* w4 = (const float4*)w;
    float4* zq4 = (float4*)zq;
#pragma unroll
    for (int p = 0; p < 4; ++p) {
        int lin = p * 256 + tid;
        int row = lin >> 6, q = lin & 63;
        zq4[(size_t)(bm0 + row) * 64 + q] = w4[(size_t)widx[row] * 64 + q];
    }
}

// ===========================================================================
// Fallback (round-5 passing LDS kernel) if ws is too small. Needs only x2/w2.
// ===========================================================================
#define BM 64
#define BN 128
#define BK 64
#define LDX 68

__global__ __launch_bounds__(256) void vq_kernel_lds(
    const float* __restrict__ x, const float* __restrict__ w,
    const float* __restrict__ x2g, const float* __restrict__ w2g,
    float* __restrict__ zout, float* __restrict__ zq) {
    __shared__ float xs[BM * LDX];
    __shared__ float ws_[BN * LDX];
    __shared__ float sw2[K_CODES];
    __shared__ float sx2[BM];
    __shared__ int widx[BM];

    const int tid = threadIdx.x;
    const int bm0 = blockIdx.x * BM;
    const int rg = tid & 15;
    const int cg = tid >> 4;

    for (int i = tid; i < K_CODES; i += 256) sw2[i] = w2g[i];
    if (tid < BM) sx2[tid] = x2g[bm0 + tid];

    float best[4];
    int bidx[4];
#pragma unroll
    for (int i = 0; i < 4; ++i) { best[i] = INFINITY; bidx[i] = 0; }

    const float4* x4 = (const float4*)x;
    const float4* w4 = (const float4*)w;

    for (int cn = 0; cn < K_CODES / BN; ++cn) {
        float acc[4][8];
#pragma unroll
        for (int i = 0; i < 4; ++i)
#pragma unroll
            for (int j = 0; j < 8; ++j) acc[i][j] = 0.f;

        for (int dk = 0; dk < DIM / BK; ++dk) {
            __syncthreads();
#pragma unroll
            for (int p = 0; p < 4; ++p) {
                int l = p * 256 + tid;
                int row = l >> 4, c4 = l & 15;
                float4 v = x4[(size_t)(bm0 + row) * (DIM / 4) + dk * (BK / 4) + c4];
                *(float4*)&xs[row * LDX + c4 * 4] = v;
            }
#pragma unroll
            for (int p = 0; p < 8; ++p) {
                int l = p * 256 + tid;
                int row = l >> 4, c4 = l & 15;
                float4 v = w4[(size_t)(cn * BN + row) * (DIM / 4) + dk * (BK / 4) + c4];
                *(float4*)&ws_[row * LDX + c4 * 4] = v;
            }
            __syncthreads();
#pragma unroll
            for (int d = 0; d < BK; d += 4) {
                float4 xv[4], wv[8];
#pragma unroll
                for (int i = 0; i < 4; ++i)
                    xv[i] = *(const float4*)&xs[(rg + 16 * i) * LDX + d];
#pragma unroll
                for (int j = 0; j < 8; ++j)
                    wv[j] = *(const float4*)&ws_[(cg + 16 * j) * LDX + d];
#pragma unroll
                for (int i = 0; i < 4; ++i)
#pragma unroll
                    for (int j = 0; j < 8; ++j) {
                        acc[i][j] = __builtin_fmaf(xv[i].x, wv[j].x, acc[i][j]);
                        acc[i][j] = __builtin_fmaf(xv[i].y, wv[j].y, acc[i][j]);
                        acc[i][j] = __builtin_fmaf(xv[i].z, wv[j].z, acc[i][j]);
                        acc[i][j] = __builtin_fmaf(xv[i].w, wv[j].w, acc[i][j]);
                    }
            }
        }
#pragma unroll
        for (int j = 0; j < 8; ++j) {
            int c = cn * BN + cg + 16 * j;
            float w2v = sw2[c];
#pragma unroll
            for (int i = 0; i < 4; ++i) {
                float t = sx2[rg + 16 * i] - 2.0f * acc[i][j];
                float s = t + w2v;
                if (s < best[i]) { best[i] = s; bidx[i] = c; }
            }
        }
    }

    __syncthreads();
    float* sval = xs;
    int* sidx = (int*)(xs + 64 * 17);
#pragma unroll
    for (int i = 0; i < 4; ++i) {
        sval[(rg + 16 * i) * 17 + cg] = best[i];
        sidx[(rg + 16 * i) * 17 + cg] = bidx[i];
    }
    __syncthreads();
    if (tid < BM) {
        float bv = INFINITY;
        int bi = 0;
        for (int c = 0; c < 16; ++c) {
            float v = sval[tid * 17 + c];
            int id = sidx[tid * 17 + c];
            if (v < bv || (v == bv && id < bi)) { bv = v; bi = id; }
        }
        widx[tid] = bi;
        zout[bm0 + tid] = (float)bi;
    }
    __syncthreads();
    float4* zq4 = (float4*)zq;
#pragma unroll
    for (int p = 0; p < 16; ++p) {
        int lin = p * 256 + tid;
        int row = lin >> 6, q = lin & 63;
        zq4[(size_t)(bm0 + row) * 64 + q] = w4[(size_t)widx[row] * 64 + q];
    }
}

extern "C" void kernel_launch(void* const* d_in, const int* in_sizes, int n_in,
                              void* d_out, int out_size, void* d_ws, size_t ws_size,
                              hipStream_t stream) {
    const float* z_e = (const float*)d_in[0];
    const float* emb = (const float*)d_in[1];
    float* x2g = (float*)d_ws;                                   // [32768]
    float* w2g = x2g + N_ROWS;                                   // [1024]
    unsigned short* whi = (unsigned short*)(w2g + K_CODES);      // [1024*256]
    unsigned short* wlo = whi + (size_t)K_CODES * DIM;           // [1024*256]
    float* zout = (float*)d_out;                                 // [32768]
    float* zq = (float*)d_out + N_ROWS;                          // [32768*256]
    // flag scratch lives in the zq region (fully overwritten by gather later)
    int* flagcnt = (int*)zq;
    int* flaglist = flagcnt + 1;

    npsumsq_kernel<<<N_ROWS / 16, 64, 0, stream>>>(z_e, x2g);
    npsumsq_kernel<<<K_CODES / 16, 64, 0, stream>>>(emb, w2g);

    if (ws_size >= WS_NEEDED) {
        zero_kernel<<<1, 64, 0, stream>>>(flagcnt);
        wsplit_kernel<<<K_CODES * DIM / 256, 256, 0, stream>>>(emb, whi, wlo);
        vq_mfma<<<N_ROWS / 64, 256, 0, stream>>>(z_e, whi, wlo, x2g, w2g,
                                                 zout, flagcnt, flaglist);
        rescue_kernel<<<128, 256, 0, stream>>>(z_e, emb, x2g, w2g,
                                               flagcnt, flaglist, zout);
        gather_kernel<<<N_ROWS / 16, 256, 0, stream>>>(zout, emb, zq);
    } else {
        vq_kernel_lds<<<N_ROWS / BM, 256, 0, stream>>>(z_e, emb, x2g, w2g, zout, zq);
    }
}